// Round 6
// baseline (32.613 us; speedup 1.0000x reference)
//
#include <hip/hip_runtime.h>

// CumulativeFlattenedLinear: per-64-timestep-window projection (C=16 -> O=16,
// per-s weight slice, first ND=16 slots zero) + causal cumsum in window + bias.
//
// v6 (v5 + weight amortization + deep per-block pipeline):
//  - 512-thread blocks, 8 waves. Wave w owns o-pair (w, w+8) for the WHOLE
//    kernel: w0[16]+w1[16] = 32 long-lived regs (the proven-resident scale;
//    >32 spills/sinks -- R2/R3/R4 evidence). Weights loaded ONCE per wave
//    (v5 reloaded 64 KB per block x 4096 blocks = 256 MB of L1/L2 traffic).
//  - Block processes 8 tiles x 4 windows = 32 windows (512 blocks total).
//    Per tile: issue next tile's 8 x-loads to regs (overlaps compute),
//    compute 4 windows, sync, ds_write next tile, sync.
//  - LDS tile 16 KiB, granule-major [c4][t:256][4c]: ds_read_b128 gives 4
//    consecutive c statically indexed, conflict-free on reads.
//  - Per window per wave: 4 ds_read_b128 (shared by both o's), 32 FMA,
//    2 DPP scans, 2 coalesced dword stores.

#define CC 16
#define TT 131072
#define OO 16
#define NK 48
#define ND 16
#define GG 2048          // windows per batch row
#define NT 8             // tiles per block
#define WPT 4            // windows per tile
#define WPB (NT * WPT)   // 32 windows per block

// 64-lane inclusive prefix sum via DPP (verified R1).
#define SCAN_STEP(CTRL, RMASK)                                                  \
  {                                                                             \
    int t_ = __builtin_amdgcn_update_dpp(0, __float_as_int(v), (CTRL), (RMASK), \
                                         0xf, true);                            \
    v += __int_as_float(t_);                                                    \
  }

__device__ __forceinline__ float wave_scan64(float v) {
  SCAN_STEP(0x111, 0xf)  // row_shr:1
  SCAN_STEP(0x112, 0xf)  // row_shr:2
  SCAN_STEP(0x114, 0xf)  // row_shr:4
  SCAN_STEP(0x118, 0xf)  // row_shr:8
  SCAN_STEP(0x142, 0xa)  // row_bcast15
  SCAN_STEP(0x143, 0xc)  // row_bcast31
  return v;
}

__global__ __launch_bounds__(512, 4) void cfl_kernel(
    const float* __restrict__ x, const float* __restrict__ weight,
    const float* __restrict__ bias, float* __restrict__ out) {
  // granule-major tile: [c4:4][t:256][4 floats] = 16 KiB
  __shared__ float tile[4 * 256 * 4];

  const int tid = threadIdx.x;
  const int lane = tid & 63;
  const int wid = tid >> 6;          // 0..7 -> o-pair (wid, wid+8)

  const int n0 = blockIdx.x * WPB;   // first window (b*GG + g)
  const int b = n0 >> 11;            // / GG  (64 blocks per b, no straddle)
  const int t00 = (n0 & (GG - 1)) * 64;

  // ---- per-wave weight slices, loaded ONCE (32 long-lived regs)
  const int o0 = wid, o1 = wid + 8;
  float w0[CC], w1[CC];
#pragma unroll
  for (int c = 0; c < CC; ++c) {
    float a = 0.f, bq = 0.f;
    if (lane >= ND) {
      a = weight[o0 * (CC * NK) + c * NK + (lane - ND)];
      bq = weight[o1 * (CC * NK) + c * NK + (lane - ND)];
    }
    asm volatile("" : "+v"(a), "+v"(bq));
    w0[c] = a;
    w1[c] = bq;
  }
  const float b0 = bias[o0];
  const float b1 = bias[o1];

  // staging role: threads 0..255 -> c=0..7 at t=st; 256..511 -> c=8..15
  const int st = tid & 255;
  const int ch = (tid >> 8) * 8;
  const float* xb = x + (size_t)b * CC * TT + t00 + st;
  float* ob = out + (size_t)b * OO * TT + t00;

  // prologue: stage tile 0
  float xs[8];
#pragma unroll
  for (int i = 0; i < 8; ++i) xs[i] = xb[(size_t)(ch + i) * TT];
#pragma unroll
  for (int i = 0; i < 8; ++i) {
    const int c = ch + i;
    tile[(((c >> 2) * 256 + st) << 2) + (c & 3)] = xs[i];
  }
  __syncthreads();

  for (int tt = 0; tt < NT; ++tt) {
    // issue next tile's loads (overlap with this tile's compute)
    if (tt + 1 < NT) {
#pragma unroll
      for (int i = 0; i < 8; ++i)
        xs[i] = xb[(size_t)(ch + i) * TT + (tt + 1) * 256];
    }

    const int tb = tt * 256;
#pragma unroll
    for (int k = 0; k < WPT; ++k) {
      const int t = k * 64 + lane;
      const float4 xq0 = *(const float4*)&tile[(0 * 256 + t) << 2];
      const float4 xq1 = *(const float4*)&tile[(1 * 256 + t) << 2];
      const float4 xq2 = *(const float4*)&tile[(2 * 256 + t) << 2];
      const float4 xq3 = *(const float4*)&tile[(3 * 256 + t) << 2];

      float p0 = 0.f, p1 = 0.f;
      p0 = fmaf(xq0.x, w0[0], p0);  p1 = fmaf(xq0.x, w1[0], p1);
      p0 = fmaf(xq0.y, w0[1], p0);  p1 = fmaf(xq0.y, w1[1], p1);
      p0 = fmaf(xq0.z, w0[2], p0);  p1 = fmaf(xq0.z, w1[2], p1);
      p0 = fmaf(xq0.w, w0[3], p0);  p1 = fmaf(xq0.w, w1[3], p1);
      p0 = fmaf(xq1.x, w0[4], p0);  p1 = fmaf(xq1.x, w1[4], p1);
      p0 = fmaf(xq1.y, w0[5], p0);  p1 = fmaf(xq1.y, w1[5], p1);
      p0 = fmaf(xq1.z, w0[6], p0);  p1 = fmaf(xq1.z, w1[6], p1);
      p0 = fmaf(xq1.w, w0[7], p0);  p1 = fmaf(xq1.w, w1[7], p1);
      p0 = fmaf(xq2.x, w0[8], p0);  p1 = fmaf(xq2.x, w1[8], p1);
      p0 = fmaf(xq2.y, w0[9], p0);  p1 = fmaf(xq2.y, w1[9], p1);
      p0 = fmaf(xq2.z, w0[10], p0); p1 = fmaf(xq2.z, w1[10], p1);
      p0 = fmaf(xq2.w, w0[11], p0); p1 = fmaf(xq2.w, w1[11], p1);
      p0 = fmaf(xq3.x, w0[12], p0); p1 = fmaf(xq3.x, w1[12], p1);
      p0 = fmaf(xq3.y, w0[13], p0); p1 = fmaf(xq3.y, w1[13], p1);
      p0 = fmaf(xq3.z, w0[14], p0); p1 = fmaf(xq3.z, w1[14], p1);
      p0 = fmaf(xq3.w, w0[15], p0); p1 = fmaf(xq3.w, w1[15], p1);

      const float cs0 = wave_scan64(p0);
      const float cs1 = wave_scan64(p1);
      ob[(size_t)o0 * TT + tb + t] = cs0 + b0;
      ob[(size_t)o1 * TT + tb + t] = cs1 + b1;
    }

    if (tt + 1 < NT) {
      __syncthreads();  // everyone done reading current tile
#pragma unroll
      for (int i = 0; i < 8; ++i) {
        const int c = ch + i;
        tile[(((c >> 2) * 256 + st) << 2) + (c & 3)] = xs[i];
      }
      __syncthreads();  // next tile visible
    }
  }
}

extern "C" void kernel_launch(void* const* d_in, const int* in_sizes, int n_in,
                              void* d_out, int out_size, void* d_ws, size_t ws_size,
                              hipStream_t stream) {
  const float* x = (const float*)d_in[0];
  const float* weight = (const float*)d_in[1];
  const float* bias = (const float*)d_in[2];
  float* out = (float*)d_out;

  // 16384 windows / 32 per block = 512 blocks of 512 threads.
  cfl_kernel<<<512, 512, 0, stream>>>(x, weight, bias, out);
}

// Round 7
// 32.563 us; speedup vs baseline: 1.0016x; 1.0016x over previous
//
#include <hip/hip_runtime.h>

// CumulativeFlattenedLinear: per-64-timestep-window projection (C=16 -> O=16,
// per-s weight slice, first ND=16 slots zero) + causal cumsum in window + bias.
//
// v7 = v6 compute core + LDS out-tile with float4 writeout.
//  - R6 lesson: weight amortization/pipeline depth didn't matter. Testing the
//    store path: v5/v6 issue scalar dword stores (256 B/wave-instr) into 16
//    interleaved strided streams; the harness fill kernel hits 6.8 TB/s with
//    16B/lane dwordx4. Here each tile's outputs are staged in a 16 KB LDS
//    out-tile [o][t] and flushed as float4 (1 KB/wave-instr, 8 KB contiguous
//    burst per o-row per block).
//  - Compute mapping unchanged (proven): lane = s, wave owns o-pair (wid,
//    wid+8) with w0[16]+w1[16] = 32 long-lived regs (>32 spills: R2/R3/R4),
//    x tile 16 KB granule-major [c4][t][4c] -> ds_read_b128 statically
//    indexed, conflict-free; DPP wave scan for the causal cumsum.
//  - 512 thr (8 waves), 8 tiles x 256 t per block, 512 blocks, 32 KB LDS.

#define CC 16
#define TT 131072
#define OO 16
#define NK 48
#define ND 16
#define GG 2048
#define NT 8             // 256-t tiles per block
#define WPT 4            // windows per tile
#define WPB (NT * WPT)   // 32 windows per block

// 64-lane inclusive prefix sum via DPP (verified R1).
#define SCAN_STEP(CTRL, RMASK)                                                  \
  {                                                                             \
    int t_ = __builtin_amdgcn_update_dpp(0, __float_as_int(v), (CTRL), (RMASK), \
                                         0xf, true);                            \
    v += __int_as_float(t_);                                                    \
  }

__device__ __forceinline__ float wave_scan64(float v) {
  SCAN_STEP(0x111, 0xf)  // row_shr:1
  SCAN_STEP(0x112, 0xf)  // row_shr:2
  SCAN_STEP(0x114, 0xf)  // row_shr:4
  SCAN_STEP(0x118, 0xf)  // row_shr:8
  SCAN_STEP(0x142, 0xa)  // row_bcast15
  SCAN_STEP(0x143, 0xc)  // row_bcast31
  return v;
}

__global__ __launch_bounds__(512, 4) void cfl_kernel(
    const float* __restrict__ x, const float* __restrict__ weight,
    const float* __restrict__ bias, float* __restrict__ out) {
  // x tile, granule-major [c4:4][t:256][4c] = 16 KiB
  __shared__ __attribute__((aligned(16))) float xt[4 * 256 * 4];
  // out tile [o:16][t:256] = 16 KiB
  __shared__ __attribute__((aligned(16))) float ot[OO * 256];

  const int tid = threadIdx.x;
  const int lane = tid & 63;
  const int wid = tid >> 6;          // 0..7 -> o-pair (wid, wid+8)

  const int n0 = blockIdx.x * WPB;   // first window (b*GG + g); no b straddle
  const int b = n0 >> 11;
  const int t00 = (n0 & (GG - 1)) * 64;

  // per-wave weight slices, loaded once (32 long-lived regs, pinned)
  const int o0 = wid, o1 = wid + 8;
  float w0[CC], w1[CC];
#pragma unroll
  for (int c = 0; c < CC; ++c) {
    float a = 0.f, bq = 0.f;
    if (lane >= ND) {
      a = weight[o0 * (CC * NK) + c * NK + (lane - ND)];
      bq = weight[o1 * (CC * NK) + c * NK + (lane - ND)];
    }
    asm volatile("" : "+v"(a), "+v"(bq));
    w0[c] = a;
    w1[c] = bq;
  }
  const float b0 = bias[o0];
  const float b1 = bias[o1];

  // staging role: threads 0..255 -> c=0..7 at t=st; 256..511 -> c=8..15
  const int st = tid & 255;
  const int ch = (tid >> 8) * 8;
  const float* xb = x + (size_t)b * CC * TT + t00 + st;
  float* ob = out + (size_t)b * OO * TT + t00;

  // prologue: global loads for tile 0
  float xs[8];
#pragma unroll
  for (int i = 0; i < 8; ++i) xs[i] = xb[(size_t)(ch + i) * TT];

  for (int tt = 0; tt < NT; ++tt) {
    // write x tile (ordered after previous compute's reads by last sync)
#pragma unroll
    for (int i = 0; i < 8; ++i) {
      const int c = ch + i;
      xt[(((c >> 2) * 256 + st) << 2) + (c & 3)] = xs[i];
    }
    __syncthreads();  // x tile visible; prev writeout's ot reads done

    // issue next tile's global loads (overlap with compute)
    if (tt + 1 < NT) {
#pragma unroll
      for (int i = 0; i < 8; ++i)
        xs[i] = xb[(size_t)(ch + i) * TT + (tt + 1) * 256];
    }

    // compute 4 windows -> ot
#pragma unroll
    for (int k = 0; k < WPT; ++k) {
      const int t = k * 64 + lane;
      const float4 xq0 = *(const float4*)&xt[(0 * 256 + t) << 2];
      const float4 xq1 = *(const float4*)&xt[(1 * 256 + t) << 2];
      const float4 xq2 = *(const float4*)&xt[(2 * 256 + t) << 2];
      const float4 xq3 = *(const float4*)&xt[(3 * 256 + t) << 2];

      float p0 = 0.f, p1 = 0.f;
      p0 = fmaf(xq0.x, w0[0], p0);  p1 = fmaf(xq0.x, w1[0], p1);
      p0 = fmaf(xq0.y, w0[1], p0);  p1 = fmaf(xq0.y, w1[1], p1);
      p0 = fmaf(xq0.z, w0[2], p0);  p1 = fmaf(xq0.z, w1[2], p1);
      p0 = fmaf(xq0.w, w0[3], p0);  p1 = fmaf(xq0.w, w1[3], p1);
      p0 = fmaf(xq1.x, w0[4], p0);  p1 = fmaf(xq1.x, w1[4], p1);
      p0 = fmaf(xq1.y, w0[5], p0);  p1 = fmaf(xq1.y, w1[5], p1);
      p0 = fmaf(xq1.z, w0[6], p0);  p1 = fmaf(xq1.z, w1[6], p1);
      p0 = fmaf(xq1.w, w0[7], p0);  p1 = fmaf(xq1.w, w1[7], p1);
      p0 = fmaf(xq2.x, w0[8], p0);  p1 = fmaf(xq2.x, w1[8], p1);
      p0 = fmaf(xq2.y, w0[9], p0);  p1 = fmaf(xq2.y, w1[9], p1);
      p0 = fmaf(xq2.z, w0[10], p0); p1 = fmaf(xq2.z, w1[10], p1);
      p0 = fmaf(xq2.w, w0[11], p0); p1 = fmaf(xq2.w, w1[11], p1);
      p0 = fmaf(xq3.x, w0[12], p0); p1 = fmaf(xq3.x, w1[12], p1);
      p0 = fmaf(xq3.y, w0[13], p0); p1 = fmaf(xq3.y, w1[13], p1);
      p0 = fmaf(xq3.z, w0[14], p0); p1 = fmaf(xq3.z, w1[14], p1);
      p0 = fmaf(xq3.w, w0[15], p0); p1 = fmaf(xq3.w, w1[15], p1);

      // ot bank = lane (stride-1) -> conflict-free
      ot[o0 * 256 + t] = wave_scan64(p0) + b0;
      ot[o1 * 256 + t] = wave_scan64(p1) + b1;
    }
    __syncthreads();  // ot visible; x-tile reads done (next ds_write safe)

    // vectorized writeout: 1 KB per wave-instr, 8 KB contiguous per o-row
    {
      const int oA = wid;            // 0..7
      const float4 vA = *(const float4*)&ot[oA * 256 + 4 * lane];
      const float4 vB = *(const float4*)&ot[(oA + 8) * 256 + 4 * lane];
      ((float4*)(ob + (size_t)oA * TT + tt * 256))[lane] = vA;
      ((float4*)(ob + (size_t)(oA + 8) * TT + tt * 256))[lane] = vB;
    }
    // next iteration's leading __syncthreads orders ot reads vs next compute
  }
}

extern "C" void kernel_launch(void* const* d_in, const int* in_sizes, int n_in,
                              void* d_out, int out_size, void* d_ws, size_t ws_size,
                              hipStream_t stream) {
  const float* x = (const float*)d_in[0];
  const float* weight = (const float*)d_in[1];
  const float* bias = (const float*)d_in[2];
  float* out = (float*)d_out;

  // 16384 windows / 32 per block = 512 blocks of 512 threads.
  cfl_kernel<<<512, 512, 0, stream>>>(x, weight, bias, out);
}